// Round 1
// baseline (523.683 us; speedup 1.0000x reference)
//
#include <hip/hip_runtime.h>
#include <hip/hip_bf16.h>

// LambdaLayer fused forward for MI355X (gfx950).
// B=32 N=4096 C=512 H=4 K=16 U=4 V=128 KS=7
// Pipeline: k0 weights->bf16 W^T | k1 MFMA GEMM qkv=x@W (bf16 out)
//           k2a/k2a2 softmax stats | k2b LN stats | k3/k3b lc | k4 output.

#define Bb   32
#define Nn   4096
#define Cc   512
#define Hh   4
#define Kk   16
#define Uu   4
#define Vv   128
#define QKVW 640
#define MTOT (Bb*Nn)
#define EPSf 1e-3f

typedef __bf16 bf16;
typedef bf16  bf16x8 __attribute__((ext_vector_type(8)));
typedef bf16  bf16x4 __attribute__((ext_vector_type(4)));
typedef float f32x4  __attribute__((ext_vector_type(4)));

// ---- workspace byte offsets (all 256-aligned); total ~175.2 MB ----
#define WT_OFF   0UL          //  640*512*2      = 655360
#define QKV_OFF  655360UL     //  131072*640*2   = 167772160
#define QMU_OFF  168427520UL  //  131072*4
#define QRS_OFF  168951808UL
#define VMU_OFF  169476096UL
#define VRS_OFF  170000384UL
#define KPM_OFF  170524672UL  //  32*8*64*4 = 65536
#define KPS_OFF  170590208UL
#define KMX_OFF  170655744UL  //  2048*4
#define KIV_OFF  170663936UL
#define LCP_OFF  170672128UL  //  32*16*2048*4 = 4194304
#define LC_OFF   174866432UL  //  32*2048*4    = 262144
// end: 175128576

__device__ inline float bf2f(bf16 x) { return (float)x; }

// ---------------- K0: build W^T bf16 (640 x 512) ----------------
__global__ __launch_bounds__(256) void k0_weights(
    const float* __restrict__ wq, const float* __restrict__ wk,
    const float* __restrict__ wv, bf16* __restrict__ wt)
{
    int idx = blockIdx.x * 256 + threadIdx.x;   // over c*640 + j
    if (idx >= Cc * QKVW) return;
    int c = idx / QKVW, j = idx % QKVW;
    float v;
    if (j < 64)       v = wq[c * 64 + j];
    else if (j < 128) v = wk[c * 64 + (j - 64)];
    else              v = wv[c * 512 + (j - 128)];
    wt[(size_t)j * Cc + c] = (bf16)v;
}

// ---------------- K1: GEMM qkv = x @ W, bf16 MFMA ----------------
// tiles 128x128, BK=64, 4 waves each 64x64 (4x4 frags of 16x16x32).
__global__ __launch_bounds__(256) void k1_gemm(
    const float* __restrict__ x, const bf16* __restrict__ wt,
    bf16* __restrict__ qkv)
{
    // XCD-chunked swizzle: 5120 blocks = 8 XCDs * 640; siblings (same A-panel,
    // 5 consecutive) stay on one XCD's L2.
    int bid = blockIdx.x;
    int swz = (bid & 7) * 640 + (bid >> 3);
    int bm = swz / 5, bn = swz % 5;
    int row0 = bm * 128, col0 = bn * 128;

    int tid  = threadIdx.x;
    int lane = tid & 63, w = tid >> 6;
    int wr = (w >> 1) * 64, wc = (w & 1) * 64;
    int l15 = lane & 15, l4 = lane >> 4;

    __shared__ __align__(16) bf16 As[128 * 72];  // +8 pad: kills 128B-stride conflicts
    __shared__ __align__(16) bf16 Bs[128 * 72];

    f32x4 acc[4][4];
#pragma unroll
    for (int m = 0; m < 4; ++m)
#pragma unroll
        for (int c = 0; c < 4; ++c) { acc[m][c][0]=0.f; acc[m][c][1]=0.f; acc[m][c][2]=0.f; acc[m][c][3]=0.f; }

    const int srow = tid >> 3;        // 0..31
    const int schk = (tid & 7) * 8;   // 0,8,..,56 (element offset)

    for (int kt = 0; kt < 8; ++kt) {
        int kb = kt * 64;
        __syncthreads();
        // stage A: 128x64 f32 -> bf16 (fused convert)
#pragma unroll
        for (int it = 0; it < 4; ++it) {
            int r = it * 32 + srow;
            const float* src = x + (size_t)(row0 + r) * Cc + kb + schk;
            f32x4 lo = *(const f32x4*)src;
            f32x4 hi = *(const f32x4*)(src + 4);
            bf16x8 pk;
            pk[0]=(bf16)lo[0]; pk[1]=(bf16)lo[1]; pk[2]=(bf16)lo[2]; pk[3]=(bf16)lo[3];
            pk[4]=(bf16)hi[0]; pk[5]=(bf16)hi[1]; pk[6]=(bf16)hi[2]; pk[7]=(bf16)hi[3];
            *(bf16x8*)&As[r * 72 + schk] = pk;
        }
        // stage B (already bf16): 128 cols x 64 k
#pragma unroll
        for (int it = 0; it < 4; ++it) {
            int cI = it * 32 + srow;
            bf16x8 bvv = *(const bf16x8*)(wt + (size_t)(col0 + cI) * Cc + kb + schk);
            *(bf16x8*)&Bs[cI * 72 + schk] = bvv;
        }
        __syncthreads();
#pragma unroll
        for (int kk = 0; kk < 2; ++kk) {
            int ko = kk * 32 + l4 * 8;
            bf16x8 aF[4], bF[4];
#pragma unroll
            for (int m = 0; m < 4; ++m)
                aF[m] = *(const bf16x8*)&As[(wr + 16 * m + l15) * 72 + ko];
#pragma unroll
            for (int c = 0; c < 4; ++c)
                bF[c] = *(const bf16x8*)&Bs[(wc + 16 * c + l15) * 72 + ko];
#pragma unroll
            for (int m = 0; m < 4; ++m)
#pragma unroll
                for (int c = 0; c < 4; ++c)
                    acc[m][c] = __builtin_amdgcn_mfma_f32_16x16x32_bf16(aF[m], bF[c], acc[m][c], 0, 0, 0);
        }
    }
    // epilogue: D row=(lane>>4)*4+r, col=lane&15 (m89-verified)
#pragma unroll
    for (int m = 0; m < 4; ++m)
#pragma unroll
        for (int c = 0; c < 4; ++c) {
            int grow = row0 + wr + 16 * m + l4 * 4;
            int gcol = col0 + wc + 16 * c + l15;
#pragma unroll
            for (int r = 0; r < 4; ++r)
                qkv[(size_t)(grow + r) * QKVW + gcol] = (bf16)acc[m][c][r];
        }
}

// ------------- K2a: k softmax partial (max, sumexp) over n-splits -------------
__global__ __launch_bounds__(256) void k2a_kpart(
    const bf16* __restrict__ qkv, float* __restrict__ kpm, float* __restrict__ kps)
{
    int ns = blockIdx.x;          // 0..7 (512 rows each)
    int b  = blockIdx.y;
    int t  = threadIdx.x;
    int c0 = (t & 7) * 8;
    int stripe = t >> 3;          // 0..31
    float m[8], s[8];
#pragma unroll
    for (int j = 0; j < 8; ++j) { m[j] = -1e30f; s[j] = 0.f; }
    for (int i = 0; i < 16; ++i) {
        int n = ns * 512 + stripe + i * 32;
        bf16x8 kv = *(const bf16x8*)(qkv + (size_t)(b * Nn + n) * QKVW + 64 + c0);
#pragma unroll
        for (int j = 0; j < 8; ++j) {
            float f = bf2f(kv[j]);
            float mn = fmaxf(m[j], f);
            s[j] = s[j] * __expf(m[j] - mn) + __expf(f - mn);
            m[j] = mn;
        }
    }
    __shared__ float pm[64 * 32], ps[64 * 32];
#pragma unroll
    for (int j = 0; j < 8; ++j) { pm[(c0 + j) * 32 + stripe] = m[j]; ps[(c0 + j) * 32 + stripe] = s[j]; }
    __syncthreads();
    if (t < 64) {
        float M = -1e30f;
        for (int i = 0; i < 32; ++i) M = fmaxf(M, pm[t * 32 + i]);
        float S = 0.f;
        for (int i = 0; i < 32; ++i) S += ps[t * 32 + i] * __expf(pm[t * 32 + i] - M);
        kpm[(b * 8 + ns) * 64 + t] = M;
        kps[(b * 8 + ns) * 64 + t] = S;
    }
}

__global__ __launch_bounds__(256) void k2a2_kfinal(
    const float* __restrict__ kpm, const float* __restrict__ kps,
    float* __restrict__ kmax, float* __restrict__ kinv)
{
    int idx = blockIdx.x * 256 + threadIdx.x;  // 2048
    if (idx >= 2048) return;
    int b = idx >> 6, c = idx & 63;
    float M = -1e30f;
#pragma unroll
    for (int ns = 0; ns < 8; ++ns) M = fmaxf(M, kpm[(b * 8 + ns) * 64 + c]);
    float S = 0.f;
#pragma unroll
    for (int ns = 0; ns < 8; ++ns) S += kps[(b * 8 + ns) * 64 + c] * __expf(kpm[(b * 8 + ns) * 64 + c] - M);
    kmax[idx] = M;
    kinv[idx] = 1.0f / S;
}

// ------------- K2b: LN stats per row for q (64) and v (512) -------------
__global__ __launch_bounds__(256) void k2b_lnstats(
    const bf16* __restrict__ qkv, float* __restrict__ qmu, float* __restrict__ qrs,
    float* __restrict__ vmu, float* __restrict__ vrs)
{
    int row = blockIdx.x * 256 + threadIdx.x;   // 131072
    const bf16* p = qkv + (size_t)row * QKVW;
    float s = 0.f, ss = 0.f;
#pragma unroll
    for (int i = 0; i < 8; ++i) {
        bf16x8 v = *(const bf16x8*)(p + i * 8);
#pragma unroll
        for (int j = 0; j < 8; ++j) { float f = bf2f(v[j]); s += f; ss += f * f; }
    }
    float mu = s * (1.f / 64.f);
    float var = ss * (1.f / 64.f) - mu * mu;
    qmu[row] = mu; qrs[row] = rsqrtf(var + EPSf);
    s = 0.f; ss = 0.f;
#pragma unroll
    for (int i = 0; i < 64; ++i) {
        bf16x8 v = *(const bf16x8*)(p + 128 + i * 8);
#pragma unroll
        for (int j = 0; j < 8; ++j) { float f = bf2f(v[j]); s += f; ss += f * f; }
    }
    mu = s * (1.f / 512.f);
    var = ss * (1.f / 512.f) - mu * mu;
    vmu[row] = mu; vrs[row] = rsqrtf(var + EPSf);
}

// ------------- K3: lc partials = sum_n softmax(k) (x) LN(v) -------------
__global__ __launch_bounds__(256) void k3_lc(
    const bf16* __restrict__ qkv, const float* __restrict__ kmax, const float* __restrict__ kinv,
    const float* __restrict__ vmu, const float* __restrict__ vrs,
    const float* __restrict__ gv, const float* __restrict__ bv,
    float* __restrict__ lcp)
{
    int ns = blockIdx.x;   // 0..15 (256 rows)
    int b  = blockIdx.y;
    int t  = threadIdx.x;

    __shared__ __align__(16) float vln[16 * 512];  // 32 KB
    __shared__ float smk[16 * 64];                 // 4 KB
    __shared__ float gvl[512], bvl[512];
    for (int i = t; i < 512; i += 256) { gvl[i] = gv[i]; bvl[i] = bv[i]; }

    int kk = t >> 4, vg = t & 15;
    float acc[8];
#pragma unroll
    for (int j = 0; j < 8; ++j) acc[j] = 0.f;

    for (int ch = 0; ch < 16; ++ch) {
        int nb = ns * 256 + ch * 16;
        __syncthreads();
        {   // stage vln: 16 rows x 512 cols
            int c0  = (t & 63) * 8;
            int nl0 = t >> 6;
#pragma unroll
            for (int i = 0; i < 4; ++i) {
                int nl = nl0 + i * 4;
                int row = b * Nn + nb + nl;
                bf16x8 v8 = *(const bf16x8*)(qkv + (size_t)row * QKVW + 128 + c0);
                float mu = vmu[row], rs = vrs[row];
#pragma unroll
                for (int j = 0; j < 8; ++j)
                    vln[nl * 512 + c0 + j] = (bf2f(v8[j]) - mu) * rs * gvl[c0 + j] + bvl[c0 + j];
            }
        }
        {   // stage smk: 16 rows x 64 ch
            int c0 = (t & 15) * 4;
            int nl = t >> 4;
            int row = b * Nn + nb + nl;
            bf16x4 k4 = *(const bf16x4*)(qkv + (size_t)row * QKVW + 64 + c0);
#pragma unroll
            for (int j = 0; j < 4; ++j)
                smk[nl * 64 + c0 + j] = __expf(bf2f(k4[j]) - kmax[b * 64 + c0 + j]) * kinv[b * 64 + c0 + j];
        }
        __syncthreads();
#pragma unroll 4
        for (int nl = 0; nl < 16; ++nl) {
#pragma unroll
            for (int u = 0; u < 4; ++u) {
                float sm = smk[nl * 64 + u * 16 + kk];
                f32x4 a = *(const f32x4*)&vln[nl * 512 + u * 128 + vg * 8];
                f32x4 c = *(const f32x4*)&vln[nl * 512 + u * 128 + vg * 8 + 4];
                acc[0] += sm * a[0]; acc[1] += sm * a[1]; acc[2] += sm * a[2]; acc[3] += sm * a[3];
                acc[4] += sm * c[0]; acc[5] += sm * c[1]; acc[6] += sm * c[2]; acc[7] += sm * c[3];
            }
        }
    }
    float* dst = lcp + (size_t)(b * 16 + ns) * 2048 + kk * 128 + vg * 8;
#pragma unroll
    for (int j = 0; j < 8; ++j) dst[j] = acc[j];
}

__global__ __launch_bounds__(256) void k3b_lcreduce(
    const float* __restrict__ lcp, float* __restrict__ lc)
{
    int idx = blockIdx.x * 256 + threadIdx.x;  // 65536
    int b = idx >> 11, cc = idx & 2047;
    float s = 0.f;
#pragma unroll
    for (int ns = 0; ns < 16; ++ns) s += lcp[(size_t)(b * 16 + ns) * 2048 + cc];
    lc[idx] = s;
}

// ------------- K4: out = yc + yp (fused LN(q), conv window on LN(v)) -------------
__global__ __launch_bounds__(256) void k4_out(
    const bf16* __restrict__ qkv, const float* __restrict__ qmu, const float* __restrict__ qrs,
    const float* __restrict__ vmu, const float* __restrict__ vrs,
    const float* __restrict__ gq, const float* __restrict__ bq,
    const float* __restrict__ gv, const float* __restrict__ bv,
    const float* __restrict__ posw, const float* __restrict__ posb,
    const float* __restrict__ lc, float* __restrict__ out)
{
    int nt = blockIdx.x;   // 0..31 (128-row tile)
    int b  = blockIdx.y;
    int t  = threadIdx.x;
    int vv = t & 127, hp = t >> 7;
    int n0 = nt * 128;

    __shared__ __align__(16) float qln[32 * 64];       // 8 KB (LN'd q chunk)
    __shared__ __align__(16) float rls[32 * 4 * 32];   // 16 KB (r + qdotb)
    __shared__ __align__(16) float pw[448];
    __shared__ __align__(16) float pb[16];
    for (int i = t; i < 448; i += 256) pw[i] = posw[i];
    if (t < 16) pb[t] = posb[t];

    // per-thread constants
    f32x4 lcr4[4];
#pragma unroll
    for (int g = 0; g < 4; ++g)
#pragma unroll
        for (int j = 0; j < 4; ++j)
            lcr4[g][j] = lc[b * 2048 + (g * 4 + j) * 128 + vv];
    f32x4 gvr, bvr;
#pragma unroll
    for (int u = 0; u < 4; ++u) { gvr[u] = gv[u * 128 + vv]; bvr[u] = bv[u * 128 + vv]; }

    auto loadrow = [&](int mrow) -> f32x4 {
        f32x4 r;
        if ((unsigned)mrow < (unsigned)Nn) {
            int row = b * Nn + mrow;
            float mu = vmu[row], rs = vrs[row];
            const bf16* pr = qkv + (size_t)row * QKVW + 128 + vv;
#pragma unroll
            for (int u = 0; u < 4; ++u)
                r[u] = (bf2f(pr[u * 128]) - mu) * rs * gvr[u] + bvr[u];
        } else {
            r[0] = 0.f; r[1] = 0.f; r[2] = 0.f; r[3] = 0.f;
        }
        return r;
    };

    // sliding window of LN(v) rows: wnd[d] = row nn-3+d   (static indices only)
    f32x4 wnd[7];
#pragma unroll
    for (int kq = 0; kq < 6; ++kq) wnd[kq] = loadrow(n0 - 3 + kq);

    for (int chk = 0; chk < 4; ++chk) {
        int nb = n0 + chk * 32;
        __syncthreads();
        {   // q chunk load + LN -> LDS
            int rl = t >> 3, c0 = (t & 7) * 8;
            int row = b * Nn + nb + rl;
            bf16x8 qv = *(const bf16x8*)(qkv + (size_t)row * QKVW + c0);
            float mu = qmu[row], rs = qrs[row];
#pragma unroll
            for (int j = 0; j < 8; ++j)
                qln[rl * 64 + c0 + j] = (bf2f(qv[j]) - mu) * rs * gq[c0 + j] + bq[c0 + j];
        }
        __syncthreads();
        {   // r phase: r[row,h][d*4+u] = sum_kk q*posw ; [28] = q . posb
            int rh = t & 127;
            int rl = rh >> 2, h = rh & 3;
            int half = t >> 7;
            f32x4 q0 = *(const f32x4*)&qln[rl * 64 + h * 16 + 0];
            f32x4 q1 = *(const f32x4*)&qln[rl * 64 + h * 16 + 4];
            f32x4 q2 = *(const f32x4*)&qln[rl * 64 + h * 16 + 8];
            f32x4 q3 = *(const f32x4*)&qln[rl * 64 + h * 16 + 12];
            int j0 = half ? 15 : 0, j1 = half ? 29 : 15;
            for (int j = j0; j < j1; ++j) {
                const float* ps = (j < 28) ? &pw[j * 16] : &pb[0];
                f32x4 p0 = *(const f32x4*)(ps + 0);
                f32x4 p1 = *(const f32x4*)(ps + 4);
                f32x4 p2 = *(const f32x4*)(ps + 8);
                f32x4 p3 = *(const f32x4*)(ps + 12);
                float d = q0[0]*p0[0] + q0[1]*p0[1] + q0[2]*p0[2] + q0[3]*p0[3]
                        + q1[0]*p1[0] + q1[1]*p1[1] + q1[2]*p1[2] + q1[3]*p1[3]
                        + q2[0]*p2[0] + q2[1]*p2[1] + q2[2]*p2[2] + q2[3]*p2[3]
                        + q3[0]*p3[0] + q3[1]*p3[1] + q3[2]*p3[2] + q3[3]*p3[3];
                rls[(rl * 4 + h) * 32 + j] = d;
            }
        }
        __syncthreads();
        // output rows
        for (int i = 0; i < 32; ++i) {
            int nn = nb + i;
            wnd[6] = loadrow(nn + 3);
#pragma unroll
            for (int hh = 0; hh < 2; ++hh) {
                int h = hp * 2 + hh;
                int rbase = (i * 4 + h) * 32;
                float acc = rls[rbase + 28];   // q . pos_b
                // yc
                f32x4 qa = *(const f32x4*)&qln[i * 64 + h * 16 + 0];
                f32x4 qb = *(const f32x4*)&qln[i * 64 + h * 16 + 4];
                f32x4 qc = *(const f32x4*)&qln[i * 64 + h * 16 + 8];
                f32x4 qd = *(const f32x4*)&qln[i * 64 + h * 16 + 12];
#pragma unroll
                for (int j = 0; j < 4; ++j) acc += qa[j] * lcr4[0][j];
#pragma unroll
                for (int j = 0; j < 4; ++j) acc += qb[j] * lcr4[1][j];
#pragma unroll
                for (int j = 0; j < 4; ++j) acc += qc[j] * lcr4[2][j];
#pragma unroll
                for (int j = 0; j < 4; ++j) acc += qd[j] * lcr4[3][j];
                // yp
#pragma unroll
                for (int d = 0; d < 7; ++d) {
                    f32x4 rr = *(const f32x4*)&rls[rbase + d * 4];
                    acc += rr[0] * wnd[d][0] + rr[1] * wnd[d][1]
                         + rr[2] * wnd[d][2] + rr[3] * wnd[d][3];
                }
                out[(size_t)(b * Nn + nn) * 512 + h * 128 + vv] = acc;
            }
            // shift window (keeps indices static)
            wnd[0] = wnd[1]; wnd[1] = wnd[2]; wnd[2] = wnd[3];
            wnd[3] = wnd[4]; wnd[4] = wnd[5]; wnd[5] = wnd[6];
        }
    }
}

extern "C" void kernel_launch(void* const* d_in, const int* in_sizes, int n_in,
                              void* d_out, int out_size, void* d_ws, size_t ws_size,
                              hipStream_t stream) {
    const float* x    = (const float*)d_in[0];
    const float* wq   = (const float*)d_in[1];
    const float* wk   = (const float*)d_in[2];
    const float* wv   = (const float*)d_in[3];
    const float* gq   = (const float*)d_in[4];
    const float* bq   = (const float*)d_in[5];
    const float* gv   = (const float*)d_in[6];
    const float* bv   = (const float*)d_in[7];
    const float* posw = (const float*)d_in[8];
    const float* posb = (const float*)d_in[9];
    float* out = (float*)d_out;

    char* ws = (char*)d_ws;
    bf16*  wt   = (bf16*)(ws + WT_OFF);
    bf16*  qkv  = (bf16*)(ws + QKV_OFF);
    float* qmu  = (float*)(ws + QMU_OFF);
    float* qrs  = (float*)(ws + QRS_OFF);
    float* vmu  = (float*)(ws + VMU_OFF);
    float* vrs  = (float*)(ws + VRS_OFF);
    float* kpm  = (float*)(ws + KPM_OFF);
    float* kps  = (float*)(ws + KPS_OFF);
    float* kmax = (float*)(ws + KMX_OFF);
    float* kinv = (float*)(ws + KIV_OFF);
    float* lcp  = (float*)(ws + LCP_OFF);
    float* lc   = (float*)(ws + LC_OFF);

    k0_weights<<<(Cc * QKVW + 255) / 256, 256, 0, stream>>>(wq, wk, wv, wt);
    k1_gemm<<<5120, 256, 0, stream>>>(x, wt, qkv);
    k2a_kpart<<<dim3(8, 32), 256, 0, stream>>>(qkv, kpm, kps);
    k2a2_kfinal<<<8, 256, 0, stream>>>(kpm, kps, kmax, kinv);
    k2b_lnstats<<<512, 256, 0, stream>>>(qkv, qmu, qrs, vmu, vrs);
    k3_lc<<<dim3(16, 32), 256, 0, stream>>>(qkv, kmax, kinv, vmu, vrs, gv, bv, lcp);
    k3b_lcreduce<<<256, 256, 0, stream>>>(lcp, lc);
    k4_out<<<dim3(32, 32), 256, 0, stream>>>(qkv, qmu, qrs, vmu, vrs, gq, bq, gv, bv,
                                             posw, posb, lc, out);
}

// Round 2
// 438.708 us; speedup vs baseline: 1.1937x; 1.1937x over previous
//
#include <hip/hip_runtime.h>
#include <hip/hip_bf16.h>

// LambdaLayer fused forward for MI355X (gfx950).
// B=32 N=4096 C=512 H=4 K=16 U=4 V=128 KS=7
// Pipeline: k0 weights->bf16 W^T | k1 MFMA GEMM qkv=x@W (bf16 out)
//           k2a/k2a2 softmax stats | k2b LN stats | k3/k3b lc | k4 MFMA output.

#define Bb   32
#define Nn   4096
#define Cc   512
#define Hh   4
#define Kk   16
#define Uu   4
#define Vv   128
#define QKVW 640
#define EPSf 1e-3f

typedef __bf16 bf16;
typedef bf16  bf16x8 __attribute__((ext_vector_type(8)));
typedef bf16  bf16x4 __attribute__((ext_vector_type(4)));
typedef float f32x4  __attribute__((ext_vector_type(4)));

// ---- workspace byte offsets (all 256-aligned); total ~175.2 MB ----
#define WT_OFF   0UL          //  640*512*2      = 655360
#define QKV_OFF  655360UL     //  131072*640*2   = 167772160
#define QMU_OFF  168427520UL  //  131072*4
#define QRS_OFF  168951808UL
#define VMU_OFF  169476096UL
#define VRS_OFF  170000384UL
#define KPM_OFF  170524672UL  //  32*8*64*4 = 65536
#define KPS_OFF  170590208UL
#define KMX_OFF  170655744UL  //  2048*4
#define KIV_OFF  170663936UL
#define LCP_OFF  170672128UL  //  32*16*2048*4 = 4194304
#define LC_OFF   174866432UL  //  32*2048*4    = 262144
// end: 175128576

__device__ inline float bf2f(bf16 x) { return (float)x; }

// ---------------- K0: build W^T bf16 (640 x 512) ----------------
__global__ __launch_bounds__(256) void k0_weights(
    const float* __restrict__ wq, const float* __restrict__ wk,
    const float* __restrict__ wv, bf16* __restrict__ wt)
{
    int idx = blockIdx.x * 256 + threadIdx.x;   // over c*640 + j
    if (idx >= Cc * QKVW) return;
    int c = idx / QKVW, j = idx % QKVW;
    float v;
    if (j < 64)       v = wq[c * 64 + j];
    else if (j < 128) v = wk[c * 64 + (j - 64)];
    else              v = wv[c * 512 + (j - 128)];
    wt[(size_t)j * Cc + c] = (bf16)v;
}

// ---------------- K1: GEMM qkv = x @ W, bf16 MFMA ----------------
__global__ __launch_bounds__(256) void k1_gemm(
    const float* __restrict__ x, const bf16* __restrict__ wt,
    bf16* __restrict__ qkv)
{
    int bid = blockIdx.x;
    int swz = (bid & 7) * 640 + (bid >> 3);
    int bm = swz / 5, bn = swz % 5;
    int row0 = bm * 128, col0 = bn * 128;

    int tid  = threadIdx.x;
    int lane = tid & 63, w = tid >> 6;
    int wr = (w >> 1) * 64, wc = (w & 1) * 64;
    int l15 = lane & 15, l4 = lane >> 4;

    __shared__ __align__(16) bf16 As[128 * 72];
    __shared__ __align__(16) bf16 Bs[128 * 72];

    f32x4 acc[4][4];
#pragma unroll
    for (int m = 0; m < 4; ++m)
#pragma unroll
        for (int c = 0; c < 4; ++c) { acc[m][c][0]=0.f; acc[m][c][1]=0.f; acc[m][c][2]=0.f; acc[m][c][3]=0.f; }

    const int srow = tid >> 3;
    const int schk = (tid & 7) * 8;

    for (int kt = 0; kt < 8; ++kt) {
        int kb = kt * 64;
        __syncthreads();
#pragma unroll
        for (int it = 0; it < 4; ++it) {
            int r = it * 32 + srow;
            const float* src = x + (size_t)(row0 + r) * Cc + kb + schk;
            f32x4 lo = *(const f32x4*)src;
            f32x4 hi = *(const f32x4*)(src + 4);
            bf16x8 pk;
            pk[0]=(bf16)lo[0]; pk[1]=(bf16)lo[1]; pk[2]=(bf16)lo[2]; pk[3]=(bf16)lo[3];
            pk[4]=(bf16)hi[0]; pk[5]=(bf16)hi[1]; pk[6]=(bf16)hi[2]; pk[7]=(bf16)hi[3];
            *(bf16x8*)&As[r * 72 + schk] = pk;
        }
#pragma unroll
        for (int it = 0; it < 4; ++it) {
            int cI = it * 32 + srow;
            bf16x8 bvv = *(const bf16x8*)(wt + (size_t)(col0 + cI) * Cc + kb + schk);
            *(bf16x8*)&Bs[cI * 72 + schk] = bvv;
        }
        __syncthreads();
#pragma unroll
        for (int kk = 0; kk < 2; ++kk) {
            int ko = kk * 32 + l4 * 8;
            bf16x8 aF[4], bF[4];
#pragma unroll
            for (int m = 0; m < 4; ++m)
                aF[m] = *(const bf16x8*)&As[(wr + 16 * m + l15) * 72 + ko];
#pragma unroll
            for (int c = 0; c < 4; ++c)
                bF[c] = *(const bf16x8*)&Bs[(wc + 16 * c + l15) * 72 + ko];
#pragma unroll
            for (int m = 0; m < 4; ++m)
#pragma unroll
                for (int c = 0; c < 4; ++c)
                    acc[m][c] = __builtin_amdgcn_mfma_f32_16x16x32_bf16(aF[m], bF[c], acc[m][c], 0, 0, 0);
        }
    }
#pragma unroll
    for (int m = 0; m < 4; ++m)
#pragma unroll
        for (int c = 0; c < 4; ++c) {
            int grow = row0 + wr + 16 * m + l4 * 4;
            int gcol = col0 + wc + 16 * c + l15;
#pragma unroll
            for (int r = 0; r < 4; ++r)
                qkv[(size_t)(grow + r) * QKVW + gcol] = (bf16)acc[m][c][r];
        }
}

// ------------- K2a: k softmax partial (max, sumexp) over n-splits -------------
__global__ __launch_bounds__(256) void k2a_kpart(
    const bf16* __restrict__ qkv, float* __restrict__ kpm, float* __restrict__ kps)
{
    int ns = blockIdx.x;
    int b  = blockIdx.y;
    int t  = threadIdx.x;
    int c0 = (t & 7) * 8;
    int stripe = t >> 3;
    float m[8], s[8];
#pragma unroll
    for (int j = 0; j < 8; ++j) { m[j] = -1e30f; s[j] = 0.f; }
    for (int i = 0; i < 16; ++i) {
        int n = ns * 512 + stripe + i * 32;
        bf16x8 kv = *(const bf16x8*)(qkv + (size_t)(b * Nn + n) * QKVW + 64 + c0);
#pragma unroll
        for (int j = 0; j < 8; ++j) {
            float f = bf2f(kv[j]);
            float mn = fmaxf(m[j], f);
            s[j] = s[j] * __expf(m[j] - mn) + __expf(f - mn);
            m[j] = mn;
        }
    }
    __shared__ float pm[64 * 32], ps[64 * 32];
#pragma unroll
    for (int j = 0; j < 8; ++j) { pm[(c0 + j) * 32 + stripe] = m[j]; ps[(c0 + j) * 32 + stripe] = s[j]; }
    __syncthreads();
    if (t < 64) {
        float M = -1e30f;
        for (int i = 0; i < 32; ++i) M = fmaxf(M, pm[t * 32 + i]);
        float S = 0.f;
        for (int i = 0; i < 32; ++i) S += ps[t * 32 + i] * __expf(pm[t * 32 + i] - M);
        kpm[(b * 8 + ns) * 64 + t] = M;
        kps[(b * 8 + ns) * 64 + t] = S;
    }
}

__global__ __launch_bounds__(256) void k2a2_kfinal(
    const float* __restrict__ kpm, const float* __restrict__ kps,
    float* __restrict__ kmax, float* __restrict__ kinv)
{
    int idx = blockIdx.x * 256 + threadIdx.x;
    if (idx >= 2048) return;
    int b = idx >> 6, c = idx & 63;
    float M = -1e30f;
#pragma unroll
    for (int ns = 0; ns < 8; ++ns) M = fmaxf(M, kpm[(b * 8 + ns) * 64 + c]);
    float S = 0.f;
#pragma unroll
    for (int ns = 0; ns < 8; ++ns) S += kps[(b * 8 + ns) * 64 + c] * __expf(kpm[(b * 8 + ns) * 64 + c] - M);
    kmax[idx] = M;
    kinv[idx] = 1.0f / S;
}

// ------------- K2b: LN stats per row for q (64) and v (512) -------------
__global__ __launch_bounds__(256) void k2b_lnstats(
    const bf16* __restrict__ qkv, float* __restrict__ qmu, float* __restrict__ qrs,
    float* __restrict__ vmu, float* __restrict__ vrs)
{
    int row = blockIdx.x * 256 + threadIdx.x;
    const bf16* p = qkv + (size_t)row * QKVW;
    float s = 0.f, ss = 0.f;
#pragma unroll
    for (int i = 0; i < 8; ++i) {
        bf16x8 v = *(const bf16x8*)(p + i * 8);
#pragma unroll
        for (int j = 0; j < 8; ++j) { float f = bf2f(v[j]); s += f; ss += f * f; }
    }
    float mu = s * (1.f / 64.f);
    float var = ss * (1.f / 64.f) - mu * mu;
    qmu[row] = mu; qrs[row] = rsqrtf(var + EPSf);
    s = 0.f; ss = 0.f;
#pragma unroll
    for (int i = 0; i < 64; ++i) {
        bf16x8 v = *(const bf16x8*)(p + 128 + i * 8);
#pragma unroll
        for (int j = 0; j < 8; ++j) { float f = bf2f(v[j]); s += f; ss += f * f; }
    }
    mu = s * (1.f / 512.f);
    var = ss * (1.f / 512.f) - mu * mu;
    vmu[row] = mu; vrs[row] = rsqrtf(var + EPSf);
}

// ------------- K3: lc partials = sum_n softmax(k) (x) LN(v) -------------
__global__ __launch_bounds__(256) void k3_lc(
    const bf16* __restrict__ qkv, const float* __restrict__ kmax, const float* __restrict__ kinv,
    const float* __restrict__ vmu, const float* __restrict__ vrs,
    const float* __restrict__ gv, const float* __restrict__ bv,
    float* __restrict__ lcp)
{
    int ns = blockIdx.x;
    int b  = blockIdx.y;
    int t  = threadIdx.x;

    __shared__ __align__(16) float vln[16 * 512];
    __shared__ float smk[16 * 64];
    __shared__ float gvl[512], bvl[512];
    for (int i = t; i < 512; i += 256) { gvl[i] = gv[i]; bvl[i] = bv[i]; }

    int kk = t >> 4, vg = t & 15;
    float acc[8];
#pragma unroll
    for (int j = 0; j < 8; ++j) acc[j] = 0.f;

    for (int ch = 0; ch < 16; ++ch) {
        int nb = ns * 256 + ch * 16;
        __syncthreads();
        {
            int c0  = (t & 63) * 8;
            int nl0 = t >> 6;
#pragma unroll
            for (int i = 0; i < 4; ++i) {
                int nl = nl0 + i * 4;
                int row = b * Nn + nb + nl;
                bf16x8 v8 = *(const bf16x8*)(qkv + (size_t)row * QKVW + 128 + c0);
                float mu = vmu[row], rs = vrs[row];
#pragma unroll
                for (int j = 0; j < 8; ++j)
                    vln[nl * 512 + c0 + j] = (bf2f(v8[j]) - mu) * rs * gvl[c0 + j] + bvl[c0 + j];
            }
        }
        {
            int c0 = (t & 15) * 4;
            int nl = t >> 4;
            int row = b * Nn + nb + nl;
            bf16x4 k4 = *(const bf16x4*)(qkv + (size_t)row * QKVW + 64 + c0);
#pragma unroll
            for (int j = 0; j < 4; ++j)
                smk[nl * 64 + c0 + j] = __expf(bf2f(k4[j]) - kmax[b * 64 + c0 + j]) * kinv[b * 64 + c0 + j];
        }
        __syncthreads();
#pragma unroll 4
        for (int nl = 0; nl < 16; ++nl) {
#pragma unroll
            for (int u = 0; u < 4; ++u) {
                float sm = smk[nl * 64 + u * 16 + kk];
                f32x4 a = *(const f32x4*)&vln[nl * 512 + u * 128 + vg * 8];
                f32x4 c = *(const f32x4*)&vln[nl * 512 + u * 128 + vg * 8 + 4];
                acc[0] += sm * a[0]; acc[1] += sm * a[1]; acc[2] += sm * a[2]; acc[3] += sm * a[3];
                acc[4] += sm * c[0]; acc[5] += sm * c[1]; acc[6] += sm * c[2]; acc[7] += sm * c[3];
            }
        }
    }
    float* dst = lcp + (size_t)(b * 16 + ns) * 2048 + kk * 128 + vg * 8;
#pragma unroll
    for (int j = 0; j < 8; ++j) dst[j] = acc[j];
}

__global__ __launch_bounds__(256) void k3b_lcreduce(
    const float* __restrict__ lcp, float* __restrict__ lc)
{
    int idx = blockIdx.x * 256 + threadIdx.x;
    int b = idx >> 11, cc = idx & 2047;
    float s = 0.f;
#pragma unroll
    for (int ns = 0; ns < 16; ++ns) s += lcp[(size_t)(b * 16 + ns) * 2048 + cc];
    lc[idx] = s;
}

// ------------- K4 (MFMA): out = yc + yp via banded-A matmul -------------
// Per block: 16 n-rows x 1 batch. Rows of the matmul = (n,h) (64), cols = v (128),
// K = 96: [0..15]=q·lc, [16]=qb·ones, [17..31]=0, [32+ri*4+du]=r (banded), rest 0.
// B in k-panel LDS layout: panel p holds B[p*8..p*8+7][v] (8 bf16 per v, b128/lane).
// Panels 0..3 = lc_ext; panels 4+rp = LN(v) ring row-pairs (rp=0..10, rows n0-3..n0+18).
#define TN4    16
#define NPAN4  15
#define PELEM  1056   // bf16 per panel (2112 B = 2048 used + 64 pad)

__global__ __launch_bounds__(256) void k4_out(
    const bf16* __restrict__ qkv, const float* __restrict__ qmu, const float* __restrict__ qrs,
    const float* __restrict__ vmu, const float* __restrict__ vrs,
    const float* __restrict__ gq, const float* __restrict__ bq,
    const float* __restrict__ gv, const float* __restrict__ bv,
    const float* __restrict__ posw, const float* __restrict__ posb,
    const float* __restrict__ lc, float* __restrict__ out)
{
    const int nt = blockIdx.x, b = blockIdx.y, t = threadIdx.x;
    const int n0 = nt * TN4;

    __shared__ __align__(16) bf16 PN[NPAN4 * PELEM]; // 31680 B  (B panels)
    __shared__ __align__(16) bf16 Ax[64 * 104];      // 13312 B  (A, stride 104 bf16 = 208 B)
    __shared__ __align__(16) bf16 PP[4 * 256];       // 2048 B   (pos_w B-panels for r-MFMA)

    // ---- phase Z: zero A and PP ----
    bf16x8 z8;
#pragma unroll
    for (int j = 0; j < 8; ++j) z8[j] = (bf16)0.f;
    for (int i = t; i < 832; i += 256) *(bf16x8*)&Ax[i * 8] = z8;
    if (t < 128) *(bf16x8*)&PP[t * 8] = z8;
    __syncthreads();

    // ---- phase F: fill PP, lc panels, ring panels, A q-part ----
    if (t < 64) {                     // pos_w panels g=0,1 (k=0..15); g=2,3 stay 0
        int g = t >> 5, du = t & 31;
        if (du < 28) {
            f32x4 a = *(const f32x4*)(posw + du * 16 + g * 8);
            f32x4 c = *(const f32x4*)(posw + du * 16 + g * 8 + 4);
            bf16x8 pk;
            pk[0]=(bf16)a[0]; pk[1]=(bf16)a[1]; pk[2]=(bf16)a[2]; pk[3]=(bf16)a[3];
            pk[4]=(bf16)c[0]; pk[5]=(bf16)c[1]; pk[6]=(bf16)c[2]; pk[7]=(bf16)c[3];
            *(bf16x8*)&PP[g * 256 + du * 8] = pk;
        }
    }
    {                                 // lc panels 0..1 + ones panel 2 + zero panel 3
        int p = t >> 7, v = t & 127;
        const float* src = lc + b * 2048 + p * 8 * 128 + v;
        bf16x8 pk;
#pragma unroll
        for (int j = 0; j < 8; ++j) pk[j] = (bf16)src[j * 128];
        *(bf16x8*)&PN[p * PELEM + v * 8] = pk;
        if (t < 128) {
            bf16x8 ones = z8; ones[0] = (bf16)1.0f;   // k=16 -> multiplies qb
            *(bf16x8*)&PN[2 * PELEM + t * 8] = ones;
            *(bf16x8*)&PN[3 * PELEM + t * 8] = z8;
        }
    }
    for (int it = t; it < 22 * 16; it += 256) {   // ring: 22 rows (n0-3..n0+18), 16 v-octets
        int lr = it >> 4, vo = it & 15;
        int n  = n0 - 3 + lr;
        int pbase = (4 + (lr >> 1)) * PELEM + (lr & 1) * 4;   // + v*8
        if ((unsigned)n < (unsigned)Nn) {
            int row = b * Nn + n;
            float mu = vmu[row], rs = vrs[row];
            float f[4][8];
#pragma unroll
            for (int u = 0; u < 4; ++u) {
                bf16x8 v8 = *(const bf16x8*)(qkv + (size_t)row * QKVW + 128 + u * 128 + vo * 8);
                f32x4 g0 = *(const f32x4*)(gv + u * 128 + vo * 8);
                f32x4 g1 = *(const f32x4*)(gv + u * 128 + vo * 8 + 4);
                f32x4 b0 = *(const f32x4*)(bv + u * 128 + vo * 8);
                f32x4 b1 = *(const f32x4*)(bv + u * 128 + vo * 8 + 4);
#pragma unroll
                for (int j = 0; j < 4; ++j) f[u][j]     = (bf2f(v8[j])     - mu) * rs * g0[j] + b0[j];
#pragma unroll
                for (int j = 0; j < 4; ++j) f[u][4 + j] = (bf2f(v8[4 + j]) - mu) * rs * g1[j] + b1[j];
            }
#pragma unroll
            for (int vi = 0; vi < 8; ++vi) {
                bf16x4 pk;
                pk[0]=(bf16)f[0][vi]; pk[1]=(bf16)f[1][vi]; pk[2]=(bf16)f[2][vi]; pk[3]=(bf16)f[3][vi];
                *(bf16x4*)&PN[pbase + (vo * 8 + vi) * 8] = pk;
            }
        } else {
            bf16x4 zz; zz[0]=(bf16)0.f; zz[1]=(bf16)0.f; zz[2]=(bf16)0.f; zz[3]=(bf16)0.f;
#pragma unroll
            for (int vi = 0; vi < 8; ++vi)
                *(bf16x4*)&PN[pbase + (vo * 8 + vi) * 8] = zz;
        }
    }
    if (t < 128) {                    // A rows: q LN (cols 0..15) + qb (col 16)
        int row = t >> 1, half = t & 1;
        int n = n0 + (row >> 2), h = row & 3;
        int gr = b * Nn + n;
        int c0 = h * 16 + half * 8;
        bf16x8 q8 = *(const bf16x8*)(qkv + (size_t)gr * QKVW + c0);
        float mu = qmu[gr], rs = qrs[gr];
        f32x4 gg0 = *(const f32x4*)(gq + c0), gg1 = *(const f32x4*)(gq + c0 + 4);
        f32x4 bb0 = *(const f32x4*)(bq + c0), bb1 = *(const f32x4*)(bq + c0 + 4);
        f32x4 pb0 = *(const f32x4*)(posb + half * 8), pb1 = *(const f32x4*)(posb + half * 8 + 4);
        float qbp = 0.f;
        bf16x8 pk;
#pragma unroll
        for (int j = 0; j < 4; ++j) {
            float f = (bf2f(q8[j]) - mu) * rs * gg0[j] + bb0[j];
            qbp += f * pb0[j]; pk[j] = (bf16)f;
        }
#pragma unroll
        for (int j = 0; j < 4; ++j) {
            float f = (bf2f(q8[4 + j]) - mu) * rs * gg1[j] + bb1[j];
            qbp += f * pb1[j]; pk[4 + j] = (bf16)f;
        }
        *(bf16x8*)&Ax[row * 104 + half * 8] = pk;
        float qb = qbp + __shfl_xor(qbp, 1);
        if (!half) Ax[row * 104 + 16] = (bf16)qb;
    }
    __syncthreads();

    // ---- per wave: row-tile rt = wave id ----
    const int lane = t & 63, rt = t >> 6;
    const int g = lane >> 4, l15 = lane & 15;
    const int arow = rt * 16 + l15;

    // r-MFMA: r[(n,h),du] = sum_k qln*pos_w  -> scatter into banded A (ri == g here)
    bf16x8 aF0 = *(const bf16x8*)&Ax[arow * 104 + g * 8];
    f32x4 zf; zf[0]=0.f; zf[1]=0.f; zf[2]=0.f; zf[3]=0.f;
#pragma unroll
    for (int ct = 0; ct < 2; ++ct) {
        bf16x8 bp = *(const bf16x8*)&PP[g * 256 + (ct * 16 + l15) * 8];
        f32x4 rf = __builtin_amdgcn_mfma_f32_16x16x32_bf16(aF0, bp, zf, 0, 0, 0);
        int du = ct * 16 + l15;
#pragma unroll
        for (int reg = 0; reg < 4; ++reg) {
            int row = rt * 16 + g * 4 + reg;   // ri = (row>>2)&3 == g
            Ax[row * 104 + 32 + g * 4 + du] = (bf16)rf[reg];
        }
    }

    // main MFMA: 3 k-steps x 8 col-tiles
    bf16x8 aF1 = *(const bf16x8*)&Ax[arow * 104 + 32 + g * 8];
    bf16x8 aF2 = *(const bf16x8*)&Ax[arow * 104 + 64 + g * 8];
    const int P1 = (4 + rt * 2 + g) * PELEM;       // s=1: ring pairs rt*2+g
    const int P2 = (4 + rt * 2 + 4) * PELEM;       // s=2: only m=8,9 real; clamped pair
    f32x4 acc[8];
#pragma unroll
    for (int c = 0; c < 8; ++c) acc[c] = zf;
#pragma unroll
    for (int c = 0; c < 8; ++c) {
        int vb = (c * 16 + l15) * 8;
        bf16x8 b0 = *(const bf16x8*)&PN[g * PELEM + vb];
        bf16x8 b1 = *(const bf16x8*)&PN[P1 + vb];
        bf16x8 b2 = *(const bf16x8*)&PN[P2 + vb];
        acc[c] = __builtin_amdgcn_mfma_f32_16x16x32_bf16(aF0, b0, acc[c], 0, 0, 0);
        acc[c] = __builtin_amdgcn_mfma_f32_16x16x32_bf16(aF1, b1, acc[c], 0, 0, 0);
        acc[c] = __builtin_amdgcn_mfma_f32_16x16x32_bf16(aF2, b2, acc[c], 0, 0, 0);
    }
    // epilogue
#pragma unroll
    for (int c = 0; c < 8; ++c) {
#pragma unroll
        for (int reg = 0; reg < 4; ++reg) {
            int row = rt * 16 + g * 4 + reg;
            int n = n0 + (row >> 2), h = row & 3;
            out[((size_t)(b * Nn + n)) * 512 + h * 128 + c * 16 + l15] = acc[c][reg];
        }
    }
}

extern "C" void kernel_launch(void* const* d_in, const int* in_sizes, int n_in,
                              void* d_out, int out_size, void* d_ws, size_t ws_size,
                              hipStream_t stream) {
    const float* x    = (const float*)d_in[0];
    const float* wq   = (const float*)d_in[1];
    const float* wk   = (const float*)d_in[2];
    const float* wv   = (const float*)d_in[3];
    const float* gq   = (const float*)d_in[4];
    const float* bq   = (const float*)d_in[5];
    const float* gv   = (const float*)d_in[6];
    const float* bv   = (const float*)d_in[7];
    const float* posw = (const float*)d_in[8];
    const float* posb = (const float*)d_in[9];
    float* out = (float*)d_out;

    char* ws = (char*)d_ws;
    bf16*  wt   = (bf16*)(ws + WT_OFF);
    bf16*  qkv  = (bf16*)(ws + QKV_OFF);
    float* qmu  = (float*)(ws + QMU_OFF);
    float* qrs  = (float*)(ws + QRS_OFF);
    float* vmu  = (float*)(ws + VMU_OFF);
    float* vrs  = (float*)(ws + VRS_OFF);
    float* kpm  = (float*)(ws + KPM_OFF);
    float* kps  = (float*)(ws + KPS_OFF);
    float* kmax = (float*)(ws + KMX_OFF);
    float* kinv = (float*)(ws + KIV_OFF);
    float* lcp  = (float*)(ws + LCP_OFF);
    float* lc   = (float*)(ws + LC_OFF);

    k0_weights<<<(Cc * QKVW + 255) / 256, 256, 0, stream>>>(wq, wk, wv, wt);
    k1_gemm<<<5120, 256, 0, stream>>>(x, wt, qkv);
    k2a_kpart<<<dim3(8, 32), 256, 0, stream>>>(qkv, kpm, kps);
    k2a2_kfinal<<<8, 256, 0, stream>>>(kpm, kps, kmax, kinv);
    k2b_lnstats<<<512, 256, 0, stream>>>(qkv, qmu, qrs, vmu, vrs);
    k3_lc<<<dim3(16, 32), 256, 0, stream>>>(qkv, kmax, kinv, vmu, vrs, gv, bv, lcp);
    k3b_lcreduce<<<256, 256, 0, stream>>>(lcp, lc);
    k4_out<<<dim3(Nn / TN4, Bb), 256, 0, stream>>>(qkv, qmu, qrs, vmu, vrs, gq, bq, gv, bv,
                                                   posw, posb, lc, out);
}